// Round 1
// 1020.481 us; speedup vs baseline: 1.0736x; 1.0736x over previous
//
#include <hip/hip_runtime.h>
#include <hip/hip_bf16.h>

// Problem: B=64, n=SIZE_IN=1024, m=SIZE_OUT=1024.
// Inputs:  [0] mu_in (64,1024) f32   [1] sigma_in (64,1024,1024) f32
//          [2] w_mu (1024,1024) f32 [i][o]   [3] w_sigma (1024,1024) f32 [o][i]
//          [4] b_mu (1024,1) f32    [5] b_sigma (1024,) f32
// Outputs (flat concat, f32): mu_out (65536) | Sigma_out (67108864) | w_kl | b_kl
//
// R1 change: Sigma_out = W^T Sigma W is symmetric (sigma_in is PSD/symmetric by
// construction). k_gemmB now computes only the 36 upper-triangular tile-pairs
// (ot <= pt) per batch instead of all 64, mirroring off-diagonal tiles on store
// (float4 mirror store). 0.5625x the MFMA work; write bytes unchanged.

typedef short bf16x8 __attribute__((ext_vector_type(8)));
typedef float f32x4  __attribute__((ext_vector_type(4)));
typedef unsigned short u16x8 __attribute__((ext_vector_type(8)));

__device__ __forceinline__ unsigned short f2bf(float f) {
    union { float f; unsigned u; } a; a.f = f;
    unsigned u = a.u;
    u += 0x7fffu + ((u >> 16) & 1u);   // round-to-nearest-even
    return (unsigned short)(u >> 16);
}

__device__ __forceinline__ float softplus_eps(float x) {
    return fmaxf(x, 0.f) + log1pf(expf(-fabsf(x))) + 1e-6f;
}

// async global -> LDS, 16 bytes/lane. LDS dest is wave-uniform base + lane*16;
// our staging index maps thread t -> LDS element t*8 within each 4KB pass, so
// each wave's 64 lanes cover a contiguous 1KB chunk in lane order. [m97 recipe]
__device__ __forceinline__ void gload_lds16(const unsigned short* g, unsigned short* l) {
    __builtin_amdgcn_global_load_lds(
        (const __attribute__((address_space(1))) void*)g,
        (__attribute__((address_space(3))) void*)l, 16, 0, 0);
}

// ---------------- small kernels ----------------

__global__ void k_zero(float* acc) {
    if (threadIdx.x < 16) acc[threadIdx.x] = 0.f;
}

// sigma f32 -> bf16 (into d_out's Sigma region, dead until gemmB overwrites it)
__global__ void k_convert(const float* __restrict__ src, unsigned short* __restrict__ dst) {
    const size_t i = ((size_t)blockIdx.x * 256 + threadIdx.x) * 8;
    const float4 a = *(const float4*)(src + i);
    const float4 b = *(const float4*)(src + i + 4);
    u16x8 h;
    h[0] = f2bf(a.x); h[1] = f2bf(a.y); h[2] = f2bf(a.z); h[3] = f2bf(a.w);
    h[4] = f2bf(b.x); h[5] = f2bf(b.y); h[6] = f2bf(b.z); h[7] = f2bf(b.w);
    *(u16x8*)(dst + i) = h;
}

// transpose w_mu [i][o] -> wT [o][i] (f32 + bf16); accumulate sum(w_mu^2) -> acc[1]
__global__ void k_transpose(const float* __restrict__ wmu, float* __restrict__ wT32,
                            unsigned short* __restrict__ wTb, float* __restrict__ acc) {
    __shared__ float tile[64][65];
    const int bx = blockIdx.x;   // i-tile
    const int by = blockIdx.y;   // o-tile
    const int t = threadIdx.x;
    const int r = t >> 4;            // 0..15
    const int c4 = (t & 15) * 4;     // 0..60
    float s = 0.f;
#pragma unroll
    for (int p = 0; p < 4; ++p) {
        const int row = r + p * 16;
        const float4 v = *(const float4*)(wmu + (size_t)(bx * 64 + row) * 1024 + by * 64 + c4);
        tile[row][c4 + 0] = v.x; tile[row][c4 + 1] = v.y;
        tile[row][c4 + 2] = v.z; tile[row][c4 + 3] = v.w;
        s += v.x * v.x + v.y * v.y + v.z * v.z + v.w * v.w;
    }
    __syncthreads();
#pragma unroll
    for (int p = 0; p < 4; ++p) {
        const int row = r + p * 16;  // local o index
        float4 o;
        o.x = tile[c4 + 0][row]; o.y = tile[c4 + 1][row];
        o.z = tile[c4 + 2][row]; o.w = tile[c4 + 3][row];
        const size_t off = (size_t)(by * 64 + row) * 1024 + bx * 64 + c4;
        *(float4*)(wT32 + off) = o;
        ushort4 h; h.x = f2bf(o.x); h.y = f2bf(o.y); h.z = f2bf(o.z); h.w = f2bf(o.w);
        *(ushort4*)(wTb + off) = h;
    }
#pragma unroll
    for (int off = 32; off; off >>= 1) s += __shfl_down(s, off, 64);
    if ((t & 63) == 0) atomicAdd(acc + 1, s);
}

// W_Sig = softplus(w_sigma)+1e-6 (store f32); accumulate sum(W_Sig)->acc[0], sum(log W_Sig)->acc[2]
__global__ void k_wsig(const float* __restrict__ wsg, float* __restrict__ WSig,
                       float* __restrict__ acc) {
    const int idx = (blockIdx.x * 256 + threadIdx.x) * 4;
    const float4 x = *(const float4*)(wsg + idx);
    float4 w;
    w.x = softplus_eps(x.x); w.y = softplus_eps(x.y);
    w.z = softplus_eps(x.z); w.w = softplus_eps(x.w);
    *(float4*)(WSig + idx) = w;
    float sw = w.x + w.y + w.z + w.w;
    float sl = logf(w.x) + logf(w.y) + logf(w.z) + logf(w.w);
#pragma unroll
    for (int off = 32; off; off >>= 1) {
        sw += __shfl_down(sw, off, 64);
        sl += __shfl_down(sl, off, 64);
    }
    if ((threadIdx.x & 63) == 0) { atomicAdd(acc + 0, sw); atomicAdd(acc + 2, sl); }
}

// faithful replication of the torch .view bug: dr[k*64+q] = sigma.flat[k*65600 + q]
__global__ void k_gather(const float* __restrict__ sig, float* __restrict__ dr) {
    const int tg = blockIdx.x * 256 + threadIdx.x;   // 65536 threads
    const int k = tg >> 6, q = tg & 63;
    dr[tg] = sig[(size_t)k * 65600 + q];
}

// mu_out + diag_term (trW + quad + B_Sig)
__global__ void k_small(const float* __restrict__ mu_in, const float* __restrict__ wT32,
                        const float* __restrict__ WSig, const float* __restrict__ dr,
                        const float* __restrict__ b_mu, const float* __restrict__ b_sig,
                        float* __restrict__ mu_out, float* __restrict__ dterm) {
    __shared__ float mu_s[1024];
    __shared__ float m2_s[1024];
    const int blk = blockIdx.x;
    const int b = blk >> 2;
    const int o0 = (blk & 3) * 256;
    const int t = threadIdx.x;
    const int o = o0 + t;
    for (int j = t; j < 1024; j += 256) {
        const float v = mu_in[b * 1024 + j];
        mu_s[j] = v; m2_s[j] = v * v;
    }
    __syncthreads();
    const int rowTr = b * 16 + (o >> 6);
    const int qq = o & 63;
    const float* wrow = wT32 + (size_t)o * 1024;
    const float* srow = WSig + (size_t)o * 1024;
    const float* trow = WSig + (size_t)rowTr * 1024;
    float am = 0.f, aq = 0.f, at = 0.f;
#pragma unroll 4
    for (int i = 0; i < 1024; i += 4) {
        const float4 wv = *(const float4*)(wrow + i);
        const float4 sv = *(const float4*)(srow + i);
        const float4 tv = *(const float4*)(trow + i);
        const float4 mv = *(const float4*)(&mu_s[i]);
        const float4 m2 = *(const float4*)(&m2_s[i]);
        am += wv.x * mv.x + wv.y * mv.y + wv.z * mv.z + wv.w * mv.w;
        aq += sv.x * m2.x + sv.y * m2.y + sv.z * m2.z + sv.w * m2.w;
        at += tv.x * dr[(i + 0) * 64 + qq] + tv.y * dr[(i + 1) * 64 + qq]
            + tv.z * dr[(i + 2) * 64 + qq] + tv.w * dr[(i + 3) * 64 + qq];
    }
    const float bs = softplus_eps(b_sig[o]);
    dterm[b * 1024 + o] = at + aq + bs;
    mu_out[b * 1024 + o] = am + b_mu[o];
}

// b_kl + finalize w_kl from accumulators
__global__ void k_final(const float* __restrict__ b_mu, const float* __restrict__ b_sig,
                        const float* __restrict__ acc, float* __restrict__ out) {
    __shared__ float red[3][4];
    const int t = threadIdx.x, lane = t & 63, w = t >> 6;
    float s1 = 0.f, s2 = 0.f, s3 = 0.f;
    for (int i = t; i < 1024; i += 256) {
        const float sp = softplus_eps(b_sig[i]);
        s1 += sp; s2 += logf(sp);
        const float bm = b_mu[i]; s3 += bm * bm;
    }
#pragma unroll
    for (int off = 32; off; off >>= 1) {
        s1 += __shfl_down(s1, off, 64);
        s2 += __shfl_down(s2, off, 64);
        s3 += __shfl_down(s3, off, 64);
    }
    if (lane == 0) { red[0][w] = s1; red[1][w] = s2; red[2][w] = s3; }
    __syncthreads();
    if (t == 0) {
        const float S1 = red[0][0] + red[0][1] + red[0][2] + red[0][3];
        const float S2 = red[1][0] + red[1][1] + red[1][2] + red[1][3];
        const float S3 = red[2][0] + red[2][1] + red[2][2] + red[2][3];
        out[67174401] = 0.5f * (S1 + S3 - 1024.f - S2);                      // b_kl
        out[67174400] = 0.5f * (acc[0] + acc[1] - 1048576.f - acc[2]);       // w_kl
    }
}

// ---------------- main GEMMs (m97-style: global_load_lds + unpadded LDS) ----------------
// Stage A: T'[b][p][i] = (Sigma_b @ w_mu)[i][p], bf16, transposed store.
// grid.x = i-tile (sigma-tile owner -> all 8 p-tile siblings share XCD residue),
// grid.y = p-tile, grid.z = batch.
__global__ __launch_bounds__(256) void k_gemmA(const unsigned short* __restrict__ sigb,
                                               const unsigned short* __restrict__ wT,
                                               unsigned short* __restrict__ Tp) {
    __shared__ unsigned short As[128 * 64];
    __shared__ unsigned short Bs[128 * 64];
    const int it_ = blockIdx.x;  // i-tile
    const int pt_ = blockIdx.y;  // p-tile
    const int bz  = blockIdx.z;  // batch
    const int t = threadIdx.x;
    const int lane = t & 63, wave = t >> 6;
    const int wm = wave & 1, wn = wave >> 1;
    const int q = lane >> 4, r = lane & 15;
    const unsigned short* Ab = sigb + ((size_t)bz << 20) + (size_t)(it_ * 128) * 1024;
    const unsigned short* Bb = wT + (size_t)(pt_ * 128) * 1024;
    f32x4 acc[4][4];
#pragma unroll
    for (int a = 0; a < 4; ++a)
#pragma unroll
        for (int b2 = 0; b2 < 4; ++b2) acc[a][b2] = (f32x4){0.f, 0.f, 0.f, 0.f};
    const int srow = t >> 3;          // 0..31
    const int scol = (t & 7) * 8;     // element col within BK=64
    for (int kt = 0; kt < 16; ++kt) {
        const int k0 = kt * 64;
        __syncthreads();
#pragma unroll
        for (int ps = 0; ps < 4; ++ps) {
            const int rr = ps * 32 + srow;
            gload_lds16(Ab + (size_t)rr * 1024 + k0 + scol, &As[ps * 2048 + t * 8]);
            gload_lds16(Bb + (size_t)rr * 1024 + k0 + scol, &Bs[ps * 2048 + t * 8]);
        }
        __syncthreads();
#pragma unroll
        for (int ks = 0; ks < 2; ++ks) {
            const int ko = ks * 32 + q * 8;
            bf16x8 af[4], bf[4];
#pragma unroll
            for (int tm = 0; tm < 4; ++tm)
                af[tm] = *(const bf16x8*)(&As[(wm * 64 + tm * 16 + r) * 64 + ko]);
#pragma unroll
            for (int tn = 0; tn < 4; ++tn)
                bf[tn] = *(const bf16x8*)(&Bs[(wn * 64 + tn * 16 + r) * 64 + ko]);
#pragma unroll
            for (int tm = 0; tm < 4; ++tm)
#pragma unroll
                for (int tn = 0; tn < 4; ++tn)
                    acc[tm][tn] = __builtin_amdgcn_mfma_f32_16x16x32_bf16(
                        af[tm], bf[tn], acc[tm][tn], 0, 0, 0);
        }
    }
    unsigned short* Tb = Tp + ((size_t)bz << 20);
#pragma unroll
    for (int tm = 0; tm < 4; ++tm)
#pragma unroll
        for (int tn = 0; tn < 4; ++tn) {
            const f32x4 v = acc[tm][tn];
            const int i_e = it_ * 128 + wm * 64 + tm * 16 + q * 4;  // D row = M = i
            const int p_e = pt_ * 128 + wn * 64 + tn * 16 + r;      // D col = N = p
            ushort4 h; h.x = f2bf(v[0]); h.y = f2bf(v[1]); h.z = f2bf(v[2]); h.w = f2bf(v[3]);
            *(ushort4*)(Tb + (size_t)p_e * 1024 + i_e) = h;         // transposed store
        }
}

// Stage B: Sigma_out[b][o][p] = sum_i wT[o][i] * T'[b][p][i]  (+ diag_term on diagonal)
// Symmetric output: only tile-pairs ot <= pt are computed (36 of 64); off-diagonal
// tiles are mirrored on store (float4 mirror). grid.x = pair index, grid.z = batch.
__global__ __launch_bounds__(256) void k_gemmB(const unsigned short* __restrict__ wT,
                                               const unsigned short* __restrict__ Tp,
                                               const float* __restrict__ dterm,
                                               float* __restrict__ Cs) {
    __shared__ unsigned short As[128 * 64];
    __shared__ unsigned short Bs[128 * 64];
    // map pair index -> (ot_, pt_) with ot_ <= pt_ (36 pairs for 8 tiles)
    int ot_ = 0, rem = blockIdx.x;
    while (rem >= 8 - ot_) { rem -= 8 - ot_; ++ot_; }
    const int pt_ = ot_ + rem;
    const int bz  = blockIdx.z;  // batch
    const int t = threadIdx.x;
    const int lane = t & 63, wave = t >> 6;
    const int wm = wave & 1, wn = wave >> 1;
    const int q = lane >> 4, r = lane & 15;
    const unsigned short* Ab = wT + (size_t)(ot_ * 128) * 1024;
    const unsigned short* Bb = Tp + ((size_t)bz << 20) + (size_t)(pt_ * 128) * 1024;
    f32x4 acc[4][4];
#pragma unroll
    for (int a = 0; a < 4; ++a)
#pragma unroll
        for (int b2 = 0; b2 < 4; ++b2) acc[a][b2] = (f32x4){0.f, 0.f, 0.f, 0.f};
    const int srow = t >> 3;
    const int scol = (t & 7) * 8;
    for (int kt = 0; kt < 16; ++kt) {
        const int k0 = kt * 64;
        __syncthreads();
#pragma unroll
        for (int ps = 0; ps < 4; ++ps) {
            const int rr = ps * 32 + srow;
            gload_lds16(Ab + (size_t)rr * 1024 + k0 + scol, &As[ps * 2048 + t * 8]);
            gload_lds16(Bb + (size_t)rr * 1024 + k0 + scol, &Bs[ps * 2048 + t * 8]);
        }
        __syncthreads();
#pragma unroll
        for (int ks = 0; ks < 2; ++ks) {
            const int ko = ks * 32 + q * 8;
            bf16x8 af[4], bf[4];
#pragma unroll
            for (int tm = 0; tm < 4; ++tm)
                af[tm] = *(const bf16x8*)(&As[(wm * 64 + tm * 16 + r) * 64 + ko]);
#pragma unroll
            for (int tn = 0; tn < 4; ++tn)
                bf[tn] = *(const bf16x8*)(&Bs[(wn * 64 + tn * 16 + r) * 64 + ko]);
#pragma unroll
            for (int tm = 0; tm < 4; ++tm)
#pragma unroll
                for (int tn = 0; tn < 4; ++tn)
                    acc[tm][tn] = __builtin_amdgcn_mfma_f32_16x16x32_bf16(
                        af[tm], bf[tn], acc[tm][tn], 0, 0, 0);
        }
    }
    float* Cb = Cs + ((size_t)bz << 20);
    if (ot_ == pt_) {
        // diagonal tile: direct store only, inject diag_term on o == p
#pragma unroll
        for (int tm = 0; tm < 4; ++tm)
#pragma unroll
            for (int tn = 0; tn < 4; ++tn) {
                const f32x4 v = acc[tm][tn];
                const int o_b = ot_ * 128 + wm * 64 + tm * 16 + q * 4;
                const int p_e = pt_ * 128 + wn * 64 + tn * 16 + r;
#pragma unroll
                for (int j = 0; j < 4; ++j) {
                    const int o = o_b + j;
                    float x = v[j];
                    if (o == p_e) x += dterm[bz * 1024 + o];
                    Cb[(size_t)o * 1024 + p_e] = x;
                }
            }
    } else {
        // off-diagonal: direct store + mirrored float4 store (o != p always)
#pragma unroll
        for (int tm = 0; tm < 4; ++tm)
#pragma unroll
            for (int tn = 0; tn < 4; ++tn) {
                const f32x4 v = acc[tm][tn];
                const int o_b = ot_ * 128 + wm * 64 + tm * 16 + q * 4;
                const int p_e = pt_ * 128 + wn * 64 + tn * 16 + r;
#pragma unroll
                for (int j = 0; j < 4; ++j)
                    Cb[(size_t)(o_b + j) * 1024 + p_e] = v[j];
                *(float4*)(Cb + (size_t)p_e * 1024 + o_b) =
                    (float4){v[0], v[1], v[2], v[3]};
            }
    }
}

// ---------------- launch ----------------

extern "C" void kernel_launch(void* const* d_in, const int* in_sizes, int n_in,
                              void* d_out, int out_size, void* d_ws, size_t ws_size,
                              hipStream_t stream) {
    (void)in_sizes; (void)n_in; (void)out_size; (void)ws_size;
    const float* mu_in = (const float*)d_in[0];
    const float* sigma = (const float*)d_in[1];
    const float* w_mu  = (const float*)d_in[2];
    const float* w_sig = (const float*)d_in[3];
    const float* b_mu  = (const float*)d_in[4];
    const float* b_sg  = (const float*)d_in[5];
    float* out = (float*)d_out;

    // workspace layout (~138.6 MB)
    char* ws = (char*)d_ws;
    unsigned short* Tp   = (unsigned short*)(ws + 0x0);          // 128 MB  T' bf16
    float*          wT32 = (float*)(ws + 0x8000000);             // 4 MB
    float*          WSig = (float*)(ws + 0x8400000);             // 4 MB
    unsigned short* wTb  = (unsigned short*)(ws + 0x8800000);    // 2 MB
    float*          dr   = (float*)(ws + 0x8A00000);             // 256 KB
    float*          dt   = (float*)(ws + 0x8A40000);             // 256 KB
    float*          acc  = (float*)(ws + 0x8A80000);             // 64 B

    // bf16 sigma lives in d_out's Sigma region (dead until k_gemmB overwrites it)
    unsigned short* sigb = (unsigned short*)(out + 65536);       // 128 MB of the 256 MB region

    k_zero<<<1, 64, 0, stream>>>(acc);
    k_convert<<<32768, 256, 0, stream>>>(sigma, sigb);
    k_transpose<<<dim3(16, 16), 256, 0, stream>>>(w_mu, wT32, wTb, acc);
    k_wsig<<<1024, 256, 0, stream>>>(w_sig, WSig, acc);
    k_gather<<<256, 256, 0, stream>>>(sigma, dr);
    k_small<<<256, 256, 0, stream>>>(mu_in, wT32, WSig, dr, b_mu, b_sg, out, dt);
    k_final<<<1, 256, 0, stream>>>(b_mu, b_sg, acc, out);
    k_gemmA<<<dim3(8, 8, 64), 256, 0, stream>>>(sigb, wTb, Tp);
    k_gemmB<<<dim3(36, 1, 64), 256, 0, stream>>>(wTb, Tp, dt, out + 65536);
}

// Round 2
// 968.115 us; speedup vs baseline: 1.1317x; 1.0541x over previous
//
#include <hip/hip_runtime.h>
#include <hip/hip_bf16.h>

// Problem: B=64, n=SIZE_IN=1024, m=SIZE_OUT=1024.
// Inputs:  [0] mu_in (64,1024) f32   [1] sigma_in (64,1024,1024) f32
//          [2] w_mu (1024,1024) f32 [i][o]   [3] w_sigma (1024,1024) f32 [o][i]
//          [4] b_mu (1024,1) f32    [5] b_sigma (1024,) f32
// Outputs (flat concat, f32): mu_out (65536) | Sigma_out (67108864) | w_kl | b_kl
//
// R2 change: both GEMMs rewritten as pipelined 256x256-tile kernels (T2+T3+T4+T5):
//  - 8 waves (2Mx4N), 512 threads, BK=64, 2x(A+B) LDS buffers = 128 KiB dynamic
//  - raw asm s_barrier (no vmcnt drain) + counted s_waitcnt vmcnt(8): prefetch of
//    K-tile t+2 stays in flight across barriers (T3/T4)
//  - LDS XOR swizzle elem ^= (row&7)<<3, applied both-sides: pre-swizzled global
//    source for global_load_lds (linear dest) + swizzled ds_read (rule #21, G4)
//  - s_setprio(1) around MFMA clusters (T5)
// gemmB keeps the R1 symmetry trick (10 of 16 tile-pairs, mirror store).

typedef short bf16x8 __attribute__((ext_vector_type(8)));
typedef float f32x4  __attribute__((ext_vector_type(4)));
typedef unsigned short u16x8 __attribute__((ext_vector_type(8)));

__device__ __forceinline__ unsigned short f2bf(float f) {
    union { float f; unsigned u; } a; a.f = f;
    unsigned u = a.u;
    u += 0x7fffu + ((u >> 16) & 1u);   // round-to-nearest-even
    return (unsigned short)(u >> 16);
}

__device__ __forceinline__ float softplus_eps(float x) {
    return fmaxf(x, 0.f) + log1pf(expf(-fabsf(x))) + 1e-6f;
}

// async global -> LDS, 16 bytes/lane (wave-uniform LDS base + lane*16).
__device__ __forceinline__ void gload_lds16(const unsigned short* g, unsigned short* l) {
    __builtin_amdgcn_global_load_lds(
        (const __attribute__((address_space(1))) void*)g,
        (__attribute__((address_space(3))) void*)l, 16, 0, 0);
}

// ---------------- small kernels (unchanged) ----------------

__global__ void k_zero(float* acc) {
    if (threadIdx.x < 16) acc[threadIdx.x] = 0.f;
}

__global__ void k_convert(const float* __restrict__ src, unsigned short* __restrict__ dst) {
    const size_t i = ((size_t)blockIdx.x * 256 + threadIdx.x) * 8;
    const float4 a = *(const float4*)(src + i);
    const float4 b = *(const float4*)(src + i + 4);
    u16x8 h;
    h[0] = f2bf(a.x); h[1] = f2bf(a.y); h[2] = f2bf(a.z); h[3] = f2bf(a.w);
    h[4] = f2bf(b.x); h[5] = f2bf(b.y); h[6] = f2bf(b.z); h[7] = f2bf(b.w);
    *(u16x8*)(dst + i) = h;
}

__global__ void k_transpose(const float* __restrict__ wmu, float* __restrict__ wT32,
                            unsigned short* __restrict__ wTb, float* __restrict__ acc) {
    __shared__ float tile[64][65];
    const int bx = blockIdx.x;   // i-tile
    const int by = blockIdx.y;   // o-tile
    const int t = threadIdx.x;
    const int r = t >> 4;            // 0..15
    const int c4 = (t & 15) * 4;     // 0..60
    float s = 0.f;
#pragma unroll
    for (int p = 0; p < 4; ++p) {
        const int row = r + p * 16;
        const float4 v = *(const float4*)(wmu + (size_t)(bx * 64 + row) * 1024 + by * 64 + c4);
        tile[row][c4 + 0] = v.x; tile[row][c4 + 1] = v.y;
        tile[row][c4 + 2] = v.z; tile[row][c4 + 3] = v.w;
        s += v.x * v.x + v.y * v.y + v.z * v.z + v.w * v.w;
    }
    __syncthreads();
#pragma unroll
    for (int p = 0; p < 4; ++p) {
        const int row = r + p * 16;  // local o index
        float4 o;
        o.x = tile[c4 + 0][row]; o.y = tile[c4 + 1][row];
        o.z = tile[c4 + 2][row]; o.w = tile[c4 + 3][row];
        const size_t off = (size_t)(by * 64 + row) * 1024 + bx * 64 + c4;
        *(float4*)(wT32 + off) = o;
        ushort4 h; h.x = f2bf(o.x); h.y = f2bf(o.y); h.z = f2bf(o.z); h.w = f2bf(o.w);
        *(ushort4*)(wTb + off) = h;
    }
#pragma unroll
    for (int off = 32; off; off >>= 1) s += __shfl_down(s, off, 64);
    if ((t & 63) == 0) atomicAdd(acc + 1, s);
}

__global__ void k_wsig(const float* __restrict__ wsg, float* __restrict__ WSig,
                       float* __restrict__ acc) {
    const int idx = (blockIdx.x * 256 + threadIdx.x) * 4;
    const float4 x = *(const float4*)(wsg + idx);
    float4 w;
    w.x = softplus_eps(x.x); w.y = softplus_eps(x.y);
    w.z = softplus_eps(x.z); w.w = softplus_eps(x.w);
    *(float4*)(WSig + idx) = w;
    float sw = w.x + w.y + w.z + w.w;
    float sl = logf(w.x) + logf(w.y) + logf(w.z) + logf(w.w);
#pragma unroll
    for (int off = 32; off; off >>= 1) {
        sw += __shfl_down(sw, off, 64);
        sl += __shfl_down(sl, off, 64);
    }
    if ((threadIdx.x & 63) == 0) { atomicAdd(acc + 0, sw); atomicAdd(acc + 2, sl); }
}

// faithful replication of the torch .view bug: dr[k*64+q] = sigma.flat[k*65600 + q]
__global__ void k_gather(const float* __restrict__ sig, float* __restrict__ dr) {
    const int tg = blockIdx.x * 256 + threadIdx.x;   // 65536 threads
    const int k = tg >> 6, q = tg & 63;
    dr[tg] = sig[(size_t)k * 65600 + q];
}

__global__ void k_small(const float* __restrict__ mu_in, const float* __restrict__ wT32,
                        const float* __restrict__ WSig, const float* __restrict__ dr,
                        const float* __restrict__ b_mu, const float* __restrict__ b_sig,
                        float* __restrict__ mu_out, float* __restrict__ dterm) {
    __shared__ float mu_s[1024];
    __shared__ float m2_s[1024];
    const int blk = blockIdx.x;
    const int b = blk >> 2;
    const int o0 = (blk & 3) * 256;
    const int t = threadIdx.x;
    const int o = o0 + t;
    for (int j = t; j < 1024; j += 256) {
        const float v = mu_in[b * 1024 + j];
        mu_s[j] = v; m2_s[j] = v * v;
    }
    __syncthreads();
    const int rowTr = b * 16 + (o >> 6);
    const int qq = o & 63;
    const float* wrow = wT32 + (size_t)o * 1024;
    const float* srow = WSig + (size_t)o * 1024;
    const float* trow = WSig + (size_t)rowTr * 1024;
    float am = 0.f, aq = 0.f, at = 0.f;
#pragma unroll 4
    for (int i = 0; i < 1024; i += 4) {
        const float4 wv = *(const float4*)(wrow + i);
        const float4 sv = *(const float4*)(srow + i);
        const float4 tv = *(const float4*)(trow + i);
        const float4 mv = *(const float4*)(&mu_s[i]);
        const float4 m2 = *(const float4*)(&m2_s[i]);
        am += wv.x * mv.x + wv.y * mv.y + wv.z * mv.z + wv.w * mv.w;
        aq += sv.x * m2.x + sv.y * m2.y + sv.z * m2.z + sv.w * m2.w;
        at += tv.x * dr[(i + 0) * 64 + qq] + tv.y * dr[(i + 1) * 64 + qq]
            + tv.z * dr[(i + 2) * 64 + qq] + tv.w * dr[(i + 3) * 64 + qq];
    }
    const float bs = softplus_eps(b_sig[o]);
    dterm[b * 1024 + o] = at + aq + bs;
    mu_out[b * 1024 + o] = am + b_mu[o];
}

__global__ void k_final(const float* __restrict__ b_mu, const float* __restrict__ b_sig,
                        const float* __restrict__ acc, float* __restrict__ out) {
    __shared__ float red[3][4];
    const int t = threadIdx.x, lane = t & 63, w = t >> 6;
    float s1 = 0.f, s2 = 0.f, s3 = 0.f;
    for (int i = t; i < 1024; i += 256) {
        const float sp = softplus_eps(b_sig[i]);
        s1 += sp; s2 += logf(sp);
        const float bm = b_mu[i]; s3 += bm * bm;
    }
#pragma unroll
    for (int off = 32; off; off >>= 1) {
        s1 += __shfl_down(s1, off, 64);
        s2 += __shfl_down(s2, off, 64);
        s3 += __shfl_down(s3, off, 64);
    }
    if (lane == 0) { red[0][w] = s1; red[1][w] = s2; red[2][w] = s3; }
    __syncthreads();
    if (t == 0) {
        const float S1 = red[0][0] + red[0][1] + red[0][2] + red[0][3];
        const float S2 = red[1][0] + red[1][1] + red[1][2] + red[1][3];
        const float S3 = red[2][0] + red[2][1] + red[2][2] + red[2][3];
        out[67174401] = 0.5f * (S1 + S3 - 1024.f - S2);                      // b_kl
        out[67174400] = 0.5f * (acc[0] + acc[1] - 1048576.f - acc[2]);       // w_kl
    }
}

// ---------------- pipelined 256x256 GEMM core ----------------
// Both operands row-major, K-contiguous (C = A * B^T form), K = 1024, BK = 64.
// LDS (dynamic 128 KiB): [buf0 A | buf0 B | buf1 A | buf1 B], each 256x64 bf16.
// Swizzle: LDS element (row, c_lin) holds global col c_lin ^ ((row&7)<<3).

// stage one 256x64 tile (4 x gload_lds per thread); pre-swizzled global source.
__device__ __forceinline__ void stage_tile(const unsigned short* __restrict__ gsrc,
                                           unsigned short* ldst, int t, int k0) {
    const int tr = t >> 3;                                 // 0..63 (row within 64-row pass)
    const int swz = (((t & 7) ^ (tr & 7)) << 3);           // element offset within 64-col row
#pragma unroll
    for (int pass = 0; pass < 4; ++pass) {
        const int row = pass * 64 + tr;
        gload_lds16(gsrc + (size_t)row * 1024 + k0 + swz, ldst + pass * 4096 + t * 8);
    }
}

// compute one K-tile (BK=64) from LDS buffer into acc[8][4]
__device__ __forceinline__ void compute_tile(const unsigned short* Al, const unsigned short* Bl,
                                             f32x4 (&acc)[8][4], int wm, int wn, int q, int r) {
    const int swz = (r & 7) << 3;
#pragma unroll
    for (int ks = 0; ks < 2; ++ks) {
        const int co = (ks * 32 + q * 8) ^ swz;
        bf16x8 af[8], bv[4];
#pragma unroll
        for (int tm = 0; tm < 8; ++tm)
            af[tm] = *(const bf16x8*)(&Al[(wm * 128 + tm * 16 + r) * 64 + co]);
#pragma unroll
        for (int tn = 0; tn < 4; ++tn)
            bv[tn] = *(const bf16x8*)(&Bl[(wn * 64 + tn * 16 + r) * 64 + co]);
        __builtin_amdgcn_s_setprio(1);
#pragma unroll
        for (int tm = 0; tm < 8; ++tm)
#pragma unroll
            for (int tn = 0; tn < 4; ++tn)
                acc[tm][tn] = __builtin_amdgcn_mfma_f32_16x16x32_bf16(
                    af[tm], bv[tn], acc[tm][tn], 0, 0, 0);
        __builtin_amdgcn_s_setprio(0);
    }
}

// full K loop: counted-vmcnt double-buffer pipeline.
// Hazard ledger:
//  WAR (stage overwrites buf): stage(kt+2) issued after asm s_barrier that follows
//      this iteration's compute (all waves' ds_reads of buf done, lgkmcnt(0) drained).
//  RAW (tile ready): each wave waits vmcnt(8) (the 8 loads just issued for kt+2 may
//      be in flight; everything older incl. kt+1 has landed), then s_barrier.
//  Tail: no stage issued -> vmcnt(0).
__device__ __forceinline__ void run_gemm(const unsigned short* __restrict__ Ab,
                                         const unsigned short* __restrict__ Bb,
                                         unsigned short* lds, f32x4 (&acc)[8][4], int t) {
    const int lane = t & 63;
    const int wid = t >> 6;
    const int wm = wid >> 2, wn = wid & 3;
    const int q = lane >> 4, r = lane & 15;
#pragma unroll
    for (int a = 0; a < 8; ++a)
#pragma unroll
        for (int b = 0; b < 4; ++b) acc[a][b] = (f32x4){0.f, 0.f, 0.f, 0.f};

    // prologue: stage K-tiles 0 and 1
    stage_tile(Ab, lds + 0,     t, 0);
    stage_tile(Bb, lds + 16384, t, 0);
    stage_tile(Ab, lds + 32768, t, 64);
    stage_tile(Bb, lds + 49152, t, 64);
    asm volatile("s_waitcnt vmcnt(8)" ::: "memory");   // tile 0 landed (mine)
    asm volatile("s_barrier" ::: "memory");            // tile 0 landed (all waves)

    for (int kt = 0; kt < 16; ++kt) {
        unsigned short* buf = lds + (kt & 1) * 32768;
        compute_tile(buf, buf + 16384, acc, wm, wn, q, r);
        asm volatile("s_waitcnt lgkmcnt(0)" ::: "memory");
        __builtin_amdgcn_sched_barrier(0);
        asm volatile("s_barrier" ::: "memory");        // WAR fence: all done reading buf
        if (kt + 2 < 16) {
            stage_tile(Ab, buf, t, (kt + 2) * 64);
            stage_tile(Bb, buf + 16384, t, (kt + 2) * 64);
            asm volatile("s_waitcnt vmcnt(8)" ::: "memory");  // tile kt+1 landed (mine)
        } else {
            asm volatile("s_waitcnt vmcnt(0)" ::: "memory");  // drain at tail
        }
        asm volatile("s_barrier" ::: "memory");        // RAW fence: next tile ready (all)
    }
}

// Stage A: T'[b][p][i] = (Sigma_b @ w_mu)[i][p], bf16, transposed store.
__global__ __launch_bounds__(512) void k_gemmA(const unsigned short* __restrict__ sigb,
                                               const unsigned short* __restrict__ wT,
                                               unsigned short* __restrict__ Tp) {
    extern __shared__ unsigned short lds[];
    const int it_ = blockIdx.x;  // i-tile (256)
    const int pt_ = blockIdx.y;  // p-tile (256)
    const int bz  = blockIdx.z;  // batch
    const int t = threadIdx.x;
    const unsigned short* Ab = sigb + ((size_t)bz << 20) + (size_t)(it_ * 256) * 1024;
    const unsigned short* Bb = wT + (size_t)(pt_ * 256) * 1024;
    f32x4 acc[8][4];
    run_gemm(Ab, Bb, lds, acc, t);

    const int lane = t & 63, wid = t >> 6;
    const int wm = wid >> 2, wn = wid & 3;
    const int q = lane >> 4, r = lane & 15;
    unsigned short* Tb = Tp + ((size_t)bz << 20);
#pragma unroll
    for (int tm = 0; tm < 8; ++tm)
#pragma unroll
        for (int tn = 0; tn < 4; ++tn) {
            const f32x4 v = acc[tm][tn];
            const int i_e = it_ * 256 + wm * 128 + tm * 16 + q * 4;  // M = i
            const int p_e = pt_ * 256 + wn * 64 + tn * 16 + r;       // N = p
            ushort4 h; h.x = f2bf(v[0]); h.y = f2bf(v[1]); h.z = f2bf(v[2]); h.w = f2bf(v[3]);
            *(ushort4*)(Tb + (size_t)p_e * 1024 + i_e) = h;          // transposed store
        }
}

// Stage B: Sigma_out[b][o][p] = sum_i wT[o][i] * T'[b][p][i] (+ diag_term on diagonal).
// Symmetric: 10 upper-triangular 256-tile pairs (ot <= pt); mirror on store.
__global__ __launch_bounds__(512) void k_gemmB(const unsigned short* __restrict__ wT,
                                               const unsigned short* __restrict__ Tp,
                                               const float* __restrict__ dterm,
                                               float* __restrict__ Cs) {
    extern __shared__ unsigned short lds[];
    int ot_ = 0, rem = blockIdx.x;
    while (rem >= 4 - ot_) { rem -= 4 - ot_; ++ot_; }
    const int pt_ = ot_ + rem;
    const int bz  = blockIdx.z;
    const int t = threadIdx.x;
    const unsigned short* Ab = wT + (size_t)(ot_ * 256) * 1024;
    const unsigned short* Bb = Tp + ((size_t)bz << 20) + (size_t)(pt_ * 256) * 1024;
    f32x4 acc[8][4];
    run_gemm(Ab, Bb, lds, acc, t);

    const int lane = t & 63, wid = t >> 6;
    const int wm = wid >> 2, wn = wid & 3;
    const int q = lane >> 4, r = lane & 15;
    float* Cb = Cs + ((size_t)bz << 20);
    if (ot_ == pt_) {
        // diagonal tile: direct store only, inject diag_term on o == p
#pragma unroll
        for (int tm = 0; tm < 8; ++tm)
#pragma unroll
            for (int tn = 0; tn < 4; ++tn) {
                const f32x4 v = acc[tm][tn];
                const int o_b = ot_ * 256 + wm * 128 + tm * 16 + q * 4;
                const int p_e = pt_ * 256 + wn * 64 + tn * 16 + r;
#pragma unroll
                for (int j = 0; j < 4; ++j) {
                    const int o = o_b + j;
                    float x = v[j];
                    if (o == p_e) x += dterm[bz * 1024 + o];
                    Cb[(size_t)o * 1024 + p_e] = x;
                }
            }
    } else {
        // off-diagonal: direct store + mirrored float4 store (o != p always)
#pragma unroll
        for (int tm = 0; tm < 8; ++tm)
#pragma unroll
            for (int tn = 0; tn < 4; ++tn) {
                const f32x4 v = acc[tm][tn];
                const int o_b = ot_ * 256 + wm * 128 + tm * 16 + q * 4;
                const int p_e = pt_ * 256 + wn * 64 + tn * 16 + r;
#pragma unroll
                for (int j = 0; j < 4; ++j)
                    Cb[(size_t)(o_b + j) * 1024 + p_e] = v[j];
                *(float4*)(Cb + (size_t)p_e * 1024 + o_b) =
                    (float4){v[0], v[1], v[2], v[3]};
            }
    }
}

// ---------------- launch ----------------

extern "C" void kernel_launch(void* const* d_in, const int* in_sizes, int n_in,
                              void* d_out, int out_size, void* d_ws, size_t ws_size,
                              hipStream_t stream) {
    (void)in_sizes; (void)n_in; (void)out_size; (void)ws_size;
    const float* mu_in = (const float*)d_in[0];
    const float* sigma = (const float*)d_in[1];
    const float* w_mu  = (const float*)d_in[2];
    const float* w_sig = (const float*)d_in[3];
    const float* b_mu  = (const float*)d_in[4];
    const float* b_sg  = (const float*)d_in[5];
    float* out = (float*)d_out;

    // workspace layout (~138.6 MB)
    char* ws = (char*)d_ws;
    unsigned short* Tp   = (unsigned short*)(ws + 0x0);          // 128 MB  T' bf16
    float*          wT32 = (float*)(ws + 0x8000000);             // 4 MB
    float*          WSig = (float*)(ws + 0x8400000);             // 4 MB
    unsigned short* wTb  = (unsigned short*)(ws + 0x8800000);    // 2 MB
    float*          dr   = (float*)(ws + 0x8A00000);             // 256 KB
    float*          dt   = (float*)(ws + 0x8A40000);             // 256 KB
    float*          acc  = (float*)(ws + 0x8A80000);             // 64 B

    // bf16 sigma lives in d_out's Sigma region (dead until k_gemmB overwrites it)
    unsigned short* sigb = (unsigned short*)(out + 65536);       // 128 MB of the 256 MB region

    // allow 128 KiB dynamic LDS for the GEMM kernels (idempotent, host-side)
    static bool attr_set = false;
    if (!attr_set) {
        hipFuncSetAttribute((const void*)k_gemmA,
                            hipFuncAttributeMaxDynamicSharedMemorySize, 131072);
        hipFuncSetAttribute((const void*)k_gemmB,
                            hipFuncAttributeMaxDynamicSharedMemorySize, 131072);
        attr_set = true;
    }

    k_zero<<<1, 64, 0, stream>>>(acc);
    k_convert<<<32768, 256, 0, stream>>>(sigma, sigb);
    k_transpose<<<dim3(16, 16), 256, 0, stream>>>(w_mu, wT32, wTb, acc);
    k_wsig<<<1024, 256, 0, stream>>>(w_sig, WSig, acc);
    k_gather<<<256, 256, 0, stream>>>(sigma, dr);
    k_small<<<256, 256, 0, stream>>>(mu_in, wT32, WSig, dr, b_mu, b_sg, out, dt);
    k_final<<<1, 256, 0, stream>>>(b_mu, b_sg, acc, out);
    k_gemmA<<<dim3(4, 4, 64), 512, 131072, stream>>>(sigb, wTb, Tp);
    k_gemmB<<<dim3(10, 1, 64), 512, 131072, stream>>>(wTb, Tp, dt, out + 65536);
}

// Round 3
// 939.698 us; speedup vs baseline: 1.1659x; 1.0302x over previous
//
#include <hip/hip_runtime.h>
#include <hip/hip_bf16.h>

// Problem: B=64, n=SIZE_IN=1024, m=SIZE_OUT=1024.
// Inputs:  [0] mu_in (64,1024) f32   [1] sigma_in (64,1024,1024) f32
//          [2] w_mu (1024,1024) f32 [i][o]   [3] w_sigma (1024,1024) f32 [o][i]
//          [4] b_mu (1024,1) f32    [5] b_sigma (1024,) f32
// Outputs (flat concat, f32): mu_out (65536) | Sigma_out (67108864) | w_kl | b_kl
//
// R3 change: GEMM core reworked from depth-2/BK-64/2-barrier to
// depth-4/BK-32/1-barrier ring pipeline:
//  - 4 LDS buffers x (A 256x32 + B 256x32) bf16 = 128 KiB; buf[kt&3]
//  - while computing kt, stage kt+3 (WAR: previous tenant kt-1 consumed before
//    this K-tile's boundary barrier; RAW: kt's loads issued 3 tiles ago)
//  - boundary = counted s_waitcnt vmcnt(8) + raw s_barrier, ONE barrier/K-tile;
//    tail: vmcnt(4) @kt=30, vmcnt(0) @kt=31. Never drains mid-loop (T4).
//  - no lgkmcnt pinning: compiler's own fine-grained lgkmcnt handles
//    ds_read->MFMA (m97/m141 evidence)
//  - swizzle for 32-col rows: col-group cg = q ^ ((row>>1)&3), both-sides
//    (pre-swizzled global src for linear gload_lds dest + swizzled ds_read)
// Also: k_gather folded into k_convert (one less launch).
// gemmB keeps the symmetry trick (10 of 16 tile-pairs, mirror store).

typedef short bf16x8 __attribute__((ext_vector_type(8)));
typedef float f32x4  __attribute__((ext_vector_type(4)));
typedef unsigned short u16x8 __attribute__((ext_vector_type(8)));

__device__ __forceinline__ unsigned short f2bf(float f) {
    union { float f; unsigned u; } a; a.f = f;
    unsigned u = a.u;
    u += 0x7fffu + ((u >> 16) & 1u);   // round-to-nearest-even
    return (unsigned short)(u >> 16);
}

__device__ __forceinline__ float softplus_eps(float x) {
    return fmaxf(x, 0.f) + log1pf(expf(-fabsf(x))) + 1e-6f;
}

// async global -> LDS, 16 bytes/lane (wave-uniform LDS base + lane*16).
__device__ __forceinline__ void gload_lds16(const unsigned short* g, unsigned short* l) {
    __builtin_amdgcn_global_load_lds(
        (const __attribute__((address_space(1))) void*)g,
        (__attribute__((address_space(3))) void*)l, 16, 0, 0);
}

// ---------------- small kernels ----------------

__global__ void k_zero(float* acc) {
    if (threadIdx.x < 16) acc[threadIdx.x] = 0.f;
}

// sigma f32 -> bf16 (into d_out's Sigma region); also emits the dr gather:
// dr[k*64+q] = sigma.flat[k*65600+q] (the torch .view-bug diag rows). Since
// 65600 % 8 == 0, each dr row k is exactly 8 consecutive convert-chunks.
__global__ void k_convert(const float* __restrict__ src, unsigned short* __restrict__ dst,
                          float* __restrict__ dr) {
    const unsigned i = blockIdx.x * 256 + threadIdx.x;
    const size_t e = (size_t)i * 8;
    const float4 a = *(const float4*)(src + e);
    const float4 b = *(const float4*)(src + e + 4);
    u16x8 h;
    h[0] = f2bf(a.x); h[1] = f2bf(a.y); h[2] = f2bf(a.z); h[3] = f2bf(a.w);
    h[4] = f2bf(b.x); h[5] = f2bf(b.y); h[6] = f2bf(b.z); h[7] = f2bf(b.w);
    *(u16x8*)(dst + e) = h;
    const unsigned f8 = i * 8u;              // < 2^27, fits u32
    const unsigned k = f8 / 65600u;          // magic-mul division
    const unsigned rem = f8 - k * 65600u;
    if (rem < 64u) {
        *(float4*)(dr + k * 64 + rem) = a;
        *(float4*)(dr + k * 64 + rem + 4) = b;
    }
}

// transpose w_mu [i][o] -> wT [o][i] (f32 + bf16); accumulate sum(w_mu^2) -> acc[1]
__global__ void k_transpose(const float* __restrict__ wmu, float* __restrict__ wT32,
                            unsigned short* __restrict__ wTb, float* __restrict__ acc) {
    __shared__ float tile[64][65];
    const int bx = blockIdx.x;   // i-tile
    const int by = blockIdx.y;   // o-tile
    const int t = threadIdx.x;
    const int r = t >> 4;            // 0..15
    const int c4 = (t & 15) * 4;     // 0..60
    float s = 0.f;
#pragma unroll
    for (int p = 0; p < 4; ++p) {
        const int row = r + p * 16;
        const float4 v = *(const float4*)(wmu + (size_t)(bx * 64 + row) * 1024 + by * 64 + c4);
        tile[row][c4 + 0] = v.x; tile[row][c4 + 1] = v.y;
        tile[row][c4 + 2] = v.z; tile[row][c4 + 3] = v.w;
        s += v.x * v.x + v.y * v.y + v.z * v.z + v.w * v.w;
    }
    __syncthreads();
#pragma unroll
    for (int p = 0; p < 4; ++p) {
        const int row = r + p * 16;  // local o index
        float4 o;
        o.x = tile[c4 + 0][row]; o.y = tile[c4 + 1][row];
        o.z = tile[c4 + 2][row]; o.w = tile[c4 + 3][row];
        const size_t off = (size_t)(by * 64 + row) * 1024 + bx * 64 + c4;
        *(float4*)(wT32 + off) = o;
        ushort4 h; h.x = f2bf(o.x); h.y = f2bf(o.y); h.z = f2bf(o.z); h.w = f2bf(o.w);
        *(ushort4*)(wTb + off) = h;
    }
#pragma unroll
    for (int off = 32; off; off >>= 1) s += __shfl_down(s, off, 64);
    if ((t & 63) == 0) atomicAdd(acc + 1, s);
}

__global__ void k_wsig(const float* __restrict__ wsg, float* __restrict__ WSig,
                       float* __restrict__ acc) {
    const int idx = (blockIdx.x * 256 + threadIdx.x) * 4;
    const float4 x = *(const float4*)(wsg + idx);
    float4 w;
    w.x = softplus_eps(x.x); w.y = softplus_eps(x.y);
    w.z = softplus_eps(x.z); w.w = softplus_eps(x.w);
    *(float4*)(WSig + idx) = w;
    float sw = w.x + w.y + w.z + w.w;
    float sl = logf(w.x) + logf(w.y) + logf(w.z) + logf(w.w);
#pragma unroll
    for (int off = 32; off; off >>= 1) {
        sw += __shfl_down(sw, off, 64);
        sl += __shfl_down(sl, off, 64);
    }
    if ((threadIdx.x & 63) == 0) { atomicAdd(acc + 0, sw); atomicAdd(acc + 2, sl); }
}

__global__ void k_small(const float* __restrict__ mu_in, const float* __restrict__ wT32,
                        const float* __restrict__ WSig, const float* __restrict__ dr,
                        const float* __restrict__ b_mu, const float* __restrict__ b_sig,
                        float* __restrict__ mu_out, float* __restrict__ dterm) {
    __shared__ float mu_s[1024];
    __shared__ float m2_s[1024];
    const int blk = blockIdx.x;
    const int b = blk >> 2;
    const int o0 = (blk & 3) * 256;
    const int t = threadIdx.x;
    const int o = o0 + t;
    for (int j = t; j < 1024; j += 256) {
        const float v = mu_in[b * 1024 + j];
        mu_s[j] = v; m2_s[j] = v * v;
    }
    __syncthreads();
    const int rowTr = b * 16 + (o >> 6);
    const int qq = o & 63;
    const float* wrow = wT32 + (size_t)o * 1024;
    const float* srow = WSig + (size_t)o * 1024;
    const float* trow = WSig + (size_t)rowTr * 1024;
    float am = 0.f, aq = 0.f, at = 0.f;
#pragma unroll 4
    for (int i = 0; i < 1024; i += 4) {
        const float4 wv = *(const float4*)(wrow + i);
        const float4 sv = *(const float4*)(srow + i);
        const float4 tv = *(const float4*)(trow + i);
        const float4 mv = *(const float4*)(&mu_s[i]);
        const float4 m2 = *(const float4*)(&m2_s[i]);
        am += wv.x * mv.x + wv.y * mv.y + wv.z * mv.z + wv.w * mv.w;
        aq += sv.x * m2.x + sv.y * m2.y + sv.z * m2.z + sv.w * m2.w;
        at += tv.x * dr[(i + 0) * 64 + qq] + tv.y * dr[(i + 1) * 64 + qq]
            + tv.z * dr[(i + 2) * 64 + qq] + tv.w * dr[(i + 3) * 64 + qq];
    }
    const float bs = softplus_eps(b_sig[o]);
    dterm[b * 1024 + o] = at + aq + bs;
    mu_out[b * 1024 + o] = am + b_mu[o];
}

__global__ void k_final(const float* __restrict__ b_mu, const float* __restrict__ b_sig,
                        const float* __restrict__ acc, float* __restrict__ out) {
    __shared__ float red[3][4];
    const int t = threadIdx.x, lane = t & 63, w = t >> 6;
    float s1 = 0.f, s2 = 0.f, s3 = 0.f;
    for (int i = t; i < 1024; i += 256) {
        const float sp = softplus_eps(b_sig[i]);
        s1 += sp; s2 += logf(sp);
        const float bm = b_mu[i]; s3 += bm * bm;
    }
#pragma unroll
    for (int off = 32; off; off >>= 1) {
        s1 += __shfl_down(s1, off, 64);
        s2 += __shfl_down(s2, off, 64);
        s3 += __shfl_down(s3, off, 64);
    }
    if (lane == 0) { red[0][w] = s1; red[1][w] = s2; red[2][w] = s3; }
    __syncthreads();
    if (t == 0) {
        const float S1 = red[0][0] + red[0][1] + red[0][2] + red[0][3];
        const float S2 = red[1][0] + red[1][1] + red[1][2] + red[1][3];
        const float S3 = red[2][0] + red[2][1] + red[2][2] + red[2][3];
        out[67174401] = 0.5f * (S1 + S3 - 1024.f - S2);                      // b_kl
        out[67174400] = 0.5f * (acc[0] + acc[1] - 1048576.f - acc[2]);       // w_kl
    }
}

// ---------------- pipelined 256x256 GEMM core (depth-4 / BK=32) ----------------
// LDS: 4 buffers x 16384 shorts (A: rows 0..255 x 32 cols at +0, B same at +8192).
// Element (row, c) of a tile lives at LDS col-group (c/8) ^ ((row>>1)&3).
// Staging is linear per wave (gload_lds req); source col pre-swizzled instead.

// stage one K-tile (A+B, 4 gloads/thread) into buf[kt&3]
__device__ __forceinline__ void stage_kt(const unsigned short* __restrict__ A,
                                         const unsigned short* __restrict__ B,
                                         unsigned short* lds, int t, int kt) {
    unsigned short* buf = lds + (kt & 3) * 16384;
    const int u = t >> 2;                                  // 0..127 row-in-half
    const int swz = (((t & 3) ^ ((u >> 1) & 3)) << 3);     // pre-swizzled col offset
    const size_t k0 = (size_t)kt * 32 + swz;
    gload_lds16(A + (size_t)u * 1024 + k0,         buf + t * 8);
    gload_lds16(A + (size_t)(u + 128) * 1024 + k0, buf + 4096 + t * 8);
    gload_lds16(B + (size_t)u * 1024 + k0,         buf + 8192 + t * 8);
    gload_lds16(B + (size_t)(u + 128) * 1024 + k0, buf + 12288 + t * 8);
}

// compute one K-tile (BK=32): 12 ds_read_b128 + 32 MFMA per wave
__device__ __forceinline__ void compute_kt(const unsigned short* buf, f32x4 (&acc)[8][4],
                                           int wm, int wn, int q, int r) {
    const int co = (q ^ ((r >> 1) & 3)) * 8;               // swizzled read col
    const unsigned short* Ab = buf + (wm * 128 + r) * 32 + co;
    const unsigned short* Bb = buf + 8192 + (wn * 64 + r) * 32 + co;
    bf16x8 af[8], bv[4];
#pragma unroll
    for (int tn = 0; tn < 4; ++tn)
        bv[tn] = *(const bf16x8*)(Bb + tn * 512);          // +16 rows
#pragma unroll
    for (int tm = 0; tm < 8; ++tm)
        af[tm] = *(const bf16x8*)(Ab + tm * 512);
    __builtin_amdgcn_s_setprio(1);
#pragma unroll
    for (int tm = 0; tm < 8; ++tm)
#pragma unroll
        for (int tn = 0; tn < 4; ++tn)
            acc[tm][tn] = __builtin_amdgcn_mfma_f32_16x16x32_bf16(
                af[tm], bv[tn], acc[tm][tn], 0, 0, 0);
    __builtin_amdgcn_s_setprio(0);
}

// Hazard ledger (per K-tile kt, boundary = vmcnt + s_barrier):
//  RAW: kt's 4 loads issued during kt-3 (>=3 K-tiles of slack). vmcnt(8) allows
//       only kt+1/kt+2's 8 loads outstanding -> mine for kt landed; barrier ->
//       everyone's landed. Tail: kt=30 -> vmcnt(4); kt=31 -> vmcnt(0).
//  WAR: stage(kt+3) overwrites buf[(kt+3)&3], last read during kt-1, whose body
//       completed before this boundary barrier (consumers drained via compiler
//       lgkmcnt before their MFMAs).
__device__ __forceinline__ void run_gemm(const unsigned short* __restrict__ Ab,
                                         const unsigned short* __restrict__ Bb,
                                         unsigned short* lds, f32x4 (&acc)[8][4], int t) {
    const int lane = t & 63, wid = t >> 6;
    const int wm = wid >> 2, wn = wid & 3;
    const int q = lane >> 4, r = lane & 15;
#pragma unroll
    for (int a = 0; a < 8; ++a)
#pragma unroll
        for (int b = 0; b < 4; ++b) acc[a][b] = (f32x4){0.f, 0.f, 0.f, 0.f};

    // prologue: stage K-tiles 0,1,2 (12 gloads in flight)
    stage_kt(Ab, Bb, lds, t, 0);
    stage_kt(Ab, Bb, lds, t, 1);
    stage_kt(Ab, Bb, lds, t, 2);

    for (int kt = 0; kt < 29; ++kt) {
        asm volatile("s_waitcnt vmcnt(8)" ::: "memory");
        asm volatile("s_barrier" ::: "memory");
        stage_kt(Ab, Bb, lds, t, kt + 3);
        compute_kt(lds + (kt & 3) * 16384, acc, wm, wn, q, r);
    }
    // kt = 29: nothing left to stage; kt+1,kt+2 (8 loads) may be outstanding
    asm volatile("s_waitcnt vmcnt(8)" ::: "memory");
    asm volatile("s_barrier" ::: "memory");
    compute_kt(lds + (29 & 3) * 16384, acc, wm, wn, q, r);
    // kt = 30: only kt+1 (4 loads) may be outstanding
    asm volatile("s_waitcnt vmcnt(4)" ::: "memory");
    asm volatile("s_barrier" ::: "memory");
    compute_kt(lds + (30 & 3) * 16384, acc, wm, wn, q, r);
    // kt = 31: drain
    asm volatile("s_waitcnt vmcnt(0)" ::: "memory");
    asm volatile("s_barrier" ::: "memory");
    compute_kt(lds + (31 & 3) * 16384, acc, wm, wn, q, r);
}

// Stage A: T'[b][p][i] = (Sigma_b @ w_mu)[i][p], bf16, transposed store.
__global__ __launch_bounds__(512) void k_gemmA(const unsigned short* __restrict__ sigb,
                                               const unsigned short* __restrict__ wT,
                                               unsigned short* __restrict__ Tp) {
    extern __shared__ unsigned short lds[];
    const int it_ = blockIdx.x;  // i-tile (256)
    const int pt_ = blockIdx.y;  // p-tile (256)
    const int bz  = blockIdx.z;  // batch
    const int t = threadIdx.x;
    const unsigned short* Ab = sigb + ((size_t)bz << 20) + (size_t)(it_ * 256) * 1024;
    const unsigned short* Bb = wT + (size_t)(pt_ * 256) * 1024;
    f32x4 acc[8][4];
    run_gemm(Ab, Bb, lds, acc, t);

    const int lane = t & 63, wid = t >> 6;
    const int wm = wid >> 2, wn = wid & 3;
    const int q = lane >> 4, r = lane & 15;
    unsigned short* Tb = Tp + ((size_t)bz << 20);
#pragma unroll
    for (int tm = 0; tm < 8; ++tm)
#pragma unroll
        for (int tn = 0; tn < 4; ++tn) {
            const f32x4 v = acc[tm][tn];
            const int i_e = it_ * 256 + wm * 128 + tm * 16 + q * 4;  // M = i
            const int p_e = pt_ * 256 + wn * 64 + tn * 16 + r;       // N = p
            ushort4 h; h.x = f2bf(v[0]); h.y = f2bf(v[1]); h.z = f2bf(v[2]); h.w = f2bf(v[3]);
            *(ushort4*)(Tb + (size_t)p_e * 1024 + i_e) = h;          // transposed store
        }
}

// Stage B: Sigma_out[b][o][p] = sum_i wT[o][i] * T'[b][p][i] (+ diag_term on diagonal).
// Symmetric: 10 upper-triangular 256-tile pairs (ot <= pt); mirror on store.
__global__ __launch_bounds__(512) void k_gemmB(const unsigned short* __restrict__ wT,
                                               const unsigned short* __restrict__ Tp,
                                               const float* __restrict__ dterm,
                                               float* __restrict__ Cs) {
    extern __shared__ unsigned short lds[];
    int ot_ = 0, rem = blockIdx.x;
    while (rem >= 4 - ot_) { rem -= 4 - ot_; ++ot_; }
    const int pt_ = ot_ + rem;
    const int bz  = blockIdx.z;
    const int t = threadIdx.x;
    const unsigned short* Ab = wT + (size_t)(ot_ * 256) * 1024;
    const unsigned short* Bb = Tp + ((size_t)bz << 20) + (size_t)(pt_ * 256) * 1024;
    f32x4 acc[8][4];
    run_gemm(Ab, Bb, lds, acc, t);

    const int lane = t & 63, wid = t >> 6;
    const int wm = wid >> 2, wn = wid & 3;
    const int q = lane >> 4, r = lane & 15;
    float* Cb = Cs + ((size_t)bz << 20);
    if (ot_ == pt_) {
        // diagonal tile: direct store only, inject diag_term on o == p
#pragma unroll
        for (int tm = 0; tm < 8; ++tm)
#pragma unroll
            for (int tn = 0; tn < 4; ++tn) {
                const f32x4 v = acc[tm][tn];
                const int o_b = ot_ * 256 + wm * 128 + tm * 16 + q * 4;
                const int p_e = pt_ * 256 + wn * 64 + tn * 16 + r;
#pragma unroll
                for (int j = 0; j < 4; ++j) {
                    const int o = o_b + j;
                    float x = v[j];
                    if (o == p_e) x += dterm[bz * 1024 + o];
                    Cb[(size_t)o * 1024 + p_e] = x;
                }
            }
    } else {
        // off-diagonal: direct store + mirrored float4 store (o != p always)
#pragma unroll
        for (int tm = 0; tm < 8; ++tm)
#pragma unroll
            for (int tn = 0; tn < 4; ++tn) {
                const f32x4 v = acc[tm][tn];
                const int o_b = ot_ * 256 + wm * 128 + tm * 16 + q * 4;
                const int p_e = pt_ * 256 + wn * 64 + tn * 16 + r;
#pragma unroll
                for (int j = 0; j < 4; ++j)
                    Cb[(size_t)(o_b + j) * 1024 + p_e] = v[j];
                *(float4*)(Cb + (size_t)p_e * 1024 + o_b) =
                    (float4){v[0], v[1], v[2], v[3]};
            }
    }
}

// ---------------- launch ----------------

extern "C" void kernel_launch(void* const* d_in, const int* in_sizes, int n_in,
                              void* d_out, int out_size, void* d_ws, size_t ws_size,
                              hipStream_t stream) {
    (void)in_sizes; (void)n_in; (void)out_size; (void)ws_size;
    const float* mu_in = (const float*)d_in[0];
    const float* sigma = (const float*)d_in[1];
    const float* w_mu  = (const float*)d_in[2];
    const float* w_sig = (const float*)d_in[3];
    const float* b_mu  = (const float*)d_in[4];
    const float* b_sg  = (const float*)d_in[5];
    float* out = (float*)d_out;

    // workspace layout (~138.6 MB)
    char* ws = (char*)d_ws;
    unsigned short* Tp   = (unsigned short*)(ws + 0x0);          // 128 MB  T' bf16
    float*          wT32 = (float*)(ws + 0x8000000);             // 4 MB
    float*          WSig = (float*)(ws + 0x8400000);             // 4 MB
    unsigned short* wTb  = (unsigned short*)(ws + 0x8800000);    // 2 MB
    float*          dr   = (float*)(ws + 0x8A00000);             // 256 KB
    float*          dt   = (float*)(ws + 0x8A40000);             // 256 KB
    float*          acc  = (float*)(ws + 0x8A80000);             // 64 B

    // bf16 sigma lives in d_out's Sigma region (dead until k_gemmB overwrites it)
    unsigned short* sigb = (unsigned short*)(out + 65536);       // 128 MB of the 256 MB region

    // allow 128 KiB dynamic LDS for the GEMM kernels (idempotent, host-side)
    static bool attr_set = false;
    if (!attr_set) {
        hipFuncSetAttribute((const void*)k_gemmA,
                            hipFuncAttributeMaxDynamicSharedMemorySize, 131072);
        hipFuncSetAttribute((const void*)k_gemmB,
                            hipFuncAttributeMaxDynamicSharedMemorySize, 131072);
        attr_set = true;
    }

    k_zero<<<1, 64, 0, stream>>>(acc);
    k_convert<<<32768, 256, 0, stream>>>(sigma, sigb, dr);
    k_transpose<<<dim3(16, 16), 256, 0, stream>>>(w_mu, wT32, wTb, acc);
    k_wsig<<<1024, 256, 0, stream>>>(w_sig, WSig, acc);
    k_small<<<256, 256, 0, stream>>>(mu_in, wT32, WSig, dr, b_mu, b_sg, out, dt);
    k_final<<<1, 256, 0, stream>>>(b_mu, b_sg, acc, out);
    k_gemmA<<<dim3(4, 4, 64), 512, 131072, stream>>>(sigb, wTb, Tp);
    k_gemmB<<<dim3(10, 1, 64), 512, 131072, stream>>>(wTb, Tp, dt, out + 65536);
}